// Round 6
// baseline (2886.882 us; speedup 1.0000x reference)
//
#include <hip/hip_runtime.h>

#define BB 64
#define TT 4096
#define HH 256
#define NTOK (BB * TT)

typedef _Float16 f16;
typedef _Float16 f16x2 __attribute__((ext_vector_type(2)));
typedef unsigned int uint;
typedef unsigned short ushort;
typedef uint uint4v __attribute__((ext_vector_type(4)));

__device__ __forceinline__ f16x2 u2h(uint u) { return __builtin_bit_cast(f16x2, u); }

__device__ __forceinline__ float fdot2(f16x2 a, f16x2 b, float c) {
    return __builtin_amdgcn_fdot2(a, b, c, false);
}

__device__ __forceinline__ uint pk_rtz(float a, float b) {  // v_cvt_pkrtz_f16_f32 -> uint
    auto p = __builtin_amdgcn_cvt_pkrtz(a, b);
    return __builtin_bit_cast(uint, p);
}

__device__ __forceinline__ float dpp_xor1(float v) {  // quad_perm [1,0,3,2]
    int t = __builtin_amdgcn_update_dpp(0, __builtin_bit_cast(int, v), 0xB1, 0xF, 0xF, true);
    return __builtin_bit_cast(float, t);
}
__device__ __forceinline__ float dpp_xor2(float v) {  // quad_perm [2,3,0,1]
    int t = __builtin_amdgcn_update_dpp(0, __builtin_bit_cast(int, v), 0x4E, 0xF, 0xF, true);
    return __builtin_bit_cast(float, t);
}

__device__ __forceinline__ uint packf16(float a, float b) {  // RNE pack (prep only)
    ushort lo = __builtin_bit_cast(ushort, (f16)a);
    ushort hi = __builtin_bit_cast(ushort, (f16)b);
    return (uint)lo | ((uint)hi << 16);
}

// ============ prep: W_hh -> per-thread register blocks ============
// RNN thread tid: qd=tid>>2, s=tid&3 (K-quarter, cols [64s,64s+64)).
// Slot q (q<4) holds row 4qd + (q^s); uint i (i<32) = cols 64s+2i, 64s+2i+1.
__global__ __launch_bounds__(256) void rnn_wswz_kernel(const float* __restrict__ Whh,
                                                       uint* __restrict__ Wsw) {
    int gid = blockIdx.x * 256 + threadIdx.x;  // 256*128 uints
    if (gid >= 256 * 128) return;
    int tid = gid >> 7, rem = gid & 127;
    int q = rem >> 5, i = rem & 31;
    int qd = tid >> 2, s = tid & 3;
    int row = 4 * qd + (q ^ s);
    int col = 64 * s + 2 * i;
    Wsw[gid] = packf16(Whh[row * 256 + col], Whh[row * 256 + col + 1]);
}

// ============ prep: MLP weights, pair-interleaved + bias-in-K ============
// Lane s owns k ≡ s (mod 4). Quarter = UQ uints: j<PJ: pair (k=8j+s, 8j+4+s);
// j==PJ: (bias, 0); j>PJ: 0.  Row = 4 quarters of UQ uints.
__global__ __launch_bounds__(256) void mlp_wpad_kernel(const float* __restrict__ W,
                                                       const float* __restrict__ bsrc,
                                                       uint* __restrict__ dst,
                                                       int N, int Kreal, int PJ, int UQ) {
    int gid = blockIdx.x * 256 + threadIdx.x;
    if (gid >= N * 4 * UQ) return;
    int n = gid / (4 * UQ);
    int rem = gid - n * 4 * UQ;
    int s = rem / UQ;
    int j = rem - s * UQ;
    uint val = 0;
    if (j < PJ) {
        int k0 = 8 * j + s, k1 = 8 * j + 4 + s;
        float f0 = (k0 < Kreal) ? W[n * Kreal + k0] : 0.f;
        float f1 = (k1 < Kreal) ? W[n * Kreal + k1] : 0.f;
        val = packf16(f0, f1);
    } else if (j == PJ) {
        val = packf16(bsrc[n], 0.f);
    }
    dst[gid] = val;
}

// ============ RNN: 64 blocks x 256 threads ============
// 4-way K-split (quads), 4 rows/thread, W in 128 pinned VGPRs.
// amdgpu_waves_per_eu(1,1): occupancy pinned to 1 wave/EU -> RA gets the full
// 512-VGPR budget and has no reason to shunt W into AGPRs (R5: VGPR=104 + AGPR
// copies cost ~128 VALU insts/step).
__global__ __launch_bounds__(256) __attribute__((amdgpu_waves_per_eu(1, 1))) void rnn_kernel(
        const float* __restrict__ x, const uint* __restrict__ Wsw,
        const float* __restrict__ Wih, const float* __restrict__ bih,
        const float* __restrict__ bhh, f16* __restrict__ ht, float* __restrict__ hlast) {
    const int b = blockIdx.x, tid = threadIdx.x;
    const int s = tid & 3;
    __shared__ __align__(16) char hbuf[2][576];  // 4 quarters x 144B each
    __shared__ uint4 xs[2][128];                 // 64 rows x 32B, double-buffered

    uint4v wv[32];  // slot q = wv[q*8 .. q*8+7]
    {
        const uint4v* wp = (const uint4v*)(Wsw + (size_t)tid * 128);
#pragma unroll
        for (int i = 0; i < 32; ++i) wv[i] = wp[i];
    }
#pragma unroll
    for (int i = 0; i < 32; ++i) asm volatile("" : "+v"(wv[i]));

    float wih[7];
#pragma unroll
    for (int i = 0; i < 7; ++i) wih[i] = Wih[tid * 7 + i];
    const float bias = bih[tid] + bhh[tid];

    const float* xb = x + (size_t)b * TT * 12;
    uint4 xpre = make_uint4(0, 0, 0, 0);
    if (tid < 128) {
        int row = tid >> 1, u = tid & 1;
        xs[0][row * 2 + u] = *(const uint4*)(xb + row * 12 + u * 4);
        xpre = *(const uint4*)(xb + (64 + row) * 12 + u * 4);
    }
    if (tid < 144) ((uint*)hbuf[0])[tid] = 0;  // zero h0 (incl. pads)
    __syncthreads();

    f16* htp = ht + (size_t)b * TT * 256 + (size_t)(s * 64 + (tid >> 2));
    ushort hst[16];

    for (int tb = 0; tb < 256; ++tb) {
#pragma unroll
        for (int k = 0; k < 16; ++k) {
            const int t = tb * 16 + k;
            const int cur = k & 1;
            const int tile = (t >> 6) & 1, tstep = t & 63;

            // x contribution (wave-uniform broadcast reads)
            const float4 xa = ((const float4*)xs[tile])[tstep * 2];
            const float4 xc = ((const float4*)xs[tile])[tstep * 2 + 1];
            float xw = fmaf(xa.x, wih[0], bias);
            xw = fmaf(xa.y, wih[1], xw);
            xw = fmaf(xa.z, wih[2], xw);
            xw = fmaf(xa.w, wih[3], xw);
            xw = fmaf(xc.x, wih[4], xw);
            xw = fmaf(xc.y, wih[5], xw);
            xw = fmaf(xc.z, wih[6], xw);

            // this lane's K-quarter of h (64 f16), padded conflict-free layout
            const uint4* hq = (const uint4*)(hbuf[cur] + s * 144);
            uint hhv[32];
#pragma unroll
            for (int i = 0; i < 8; ++i) {
                uint4 v = hq[i];
                hhv[4 * i + 0] = v.x;
                hhv[4 * i + 1] = v.y;
                hhv[4 * i + 2] = v.z;
                hhv[4 * i + 3] = v.w;
            }

            float acc[4] = {0.f, 0.f, 0.f, 0.f};
#pragma unroll
            for (int q = 0; q < 4; ++q)
#pragma unroll
                for (int i = 0; i < 8; ++i) {
                    uint4v w = wv[q * 8 + i];
                    acc[q] = fdot2(u2h(hhv[4 * i + 0]), u2h(w.x), acc[q]);
                    acc[q] = fdot2(u2h(hhv[4 * i + 1]), u2h(w.y), acc[q]);
                    acc[q] = fdot2(u2h(hhv[4 * i + 2]), u2h(w.z), acc[q]);
                    acc[q] = fdot2(u2h(hhv[4 * i + 3]), u2h(w.w), acc[q]);
                }

            // slot-permuted butterfly: lane s ends with row 4qd+s == tid
            float uu = acc[0] + dpp_xor1(acc[1]);
            float vv = acc[2] + dpp_xor1(acc[3]);
            float pre = uu + dpp_xor2(vv) + xw;

            // tanh(x) = 2/(1+e^-2x) - 1
            float e = __expf(-2.0f * pre);
            float r = __builtin_amdgcn_rcpf(1.0f + e);
            float h = fmaf(2.0f, r, -1.0f);

            f16 hf = (f16)h;
            *(f16*)(hbuf[cur ^ 1] + (tid >> 6) * 144 + (tid & 63) * 2) = hf;
            hst[k] = __builtin_bit_cast(ushort, hf);
            if (k == 15 && tb == 255) hlast[b * 256 + tid] = h;

            if (tstep == 32 && tid < 128) {
                int row = tid >> 1, u = tid & 1;
                xs[tile ^ 1][row * 2 + u] = xpre;
                int nt = (t & ~63) + 128 + row;
                if (nt > TT - 1) nt = TT - 1;
                xpre = *(const uint4*)(xb + nt * 12 + u * 4);
            }
            asm volatile("s_waitcnt lgkmcnt(0)\n\ts_barrier" ::: "memory");
        }
        const size_t base = (size_t)(tb * 16) * 256;
#pragma unroll
        for (int k = 0; k < 16; ++k)
            htp[base + (size_t)k * 256] = __builtin_bit_cast(f16, hst[k]);
    }
}

// ============ MLP: 4096 blocks x 256 threads, 64 tokens/block ============
// Lane s owns k ≡ s mod 4 (z in regs). Weights LDS-staged in chunks; outputs
// selected by cndmask tree, bounced through padded LDS zbuf (dynamic index).
// n8 loops kept ROLLED (#pragma unroll 1): full unroll is ~128 KB of code vs
// 32 KB L1I -> I$ streaming stall across 12 desynchronized waves.
struct MlpP {
    const uint* w0;
    const uint* w1;
    const uint* w2;
    const uint* wt;  // L3..L6 contiguous
};

template <int UQ, int N>
__device__ __forceinline__ void layer_comp(const uint* __restrict__ wb, const uint z[36],
                                           uint* zbuf, int zoff, int tid, int s,
                                           bool s1, bool s2) {
#pragma unroll 1
    for (int n8 = 0; n8 < N / 8; ++n8) {
        float v[8];
#pragma unroll
        for (int u = 0; u < 8; ++u) {
            const uint4* wr = (const uint4*)(wb + ((n8 * 8 + u) * 4 + s) * UQ);
            float a = 0.f;
#pragma unroll
            for (int j = 0; j < UQ / 4; ++j) {
                uint4 wq = wr[j];
                a = fdot2(u2h(z[4 * j + 0]), u2h(wq.x), a);
                a = fdot2(u2h(z[4 * j + 1]), u2h(wq.y), a);
                a = fdot2(u2h(z[4 * j + 2]), u2h(wq.z), a);
                a = fdot2(u2h(z[4 * j + 3]), u2h(wq.w), a);
            }
            a += dpp_xor1(a);
            a += dpp_xor2(a);            // full quad sum on all lanes
            v[u] = fmaxf(a, 0.01f * a);  // leaky relu
        }
        float lo = s2 ? (s1 ? v[3] : v[2]) : (s1 ? v[1] : v[0]);  // v[s]
        float hi = s2 ? (s1 ? v[7] : v[6]) : (s1 ? v[5] : v[4]);  // v[s+4]
        zbuf[tid * 33 + zoff + n8] = pk_rtz(lo, hi);
    }
}

template <int UQ, int N, int CN>
__device__ __forceinline__ void layer_big(const uint* __restrict__ wg, uint* wl, uint* zbuf,
                                          const uint z[36], int tid, int s, bool s1, bool s2) {
#pragma unroll 1
    for (int c = 0; c < N / CN; ++c) {
        __syncthreads();
        const uint4* src = (const uint4*)wg + (size_t)c * (CN * UQ);
        uint4* dstv = (uint4*)wl;
        for (int idx = tid; idx < CN * UQ; idx += 256) dstv[idx] = src[idx];
        if (tid == 0) {}
        __syncthreads();
        layer_comp<UQ, CN>(wl, z, zbuf, c * (CN / 8), tid, s, s1, s2);
    }
}

__global__ __launch_bounds__(256, 3) void mlp_kernel(const f16* __restrict__ ht,
                                                     const float* __restrict__ x,
                                                     MlpP mp, float* __restrict__ out) {
    __shared__ uint zbuf[256 * 33];  // 33792 B, stride-33 conflict-free
    __shared__ uint wl[4608];        // 18432 B weight chunk
    const int tid = threadIdx.x;
    const int s = tid & 3;
    const bool s1 = (s & 1) != 0, s2 = (s & 2) != 0;
    const size_t tok = (size_t)blockIdx.x * 64 + (tid >> 2);
    const uint bz = (s == 0) ? 0x00003C00u : 0u;  // f16 1.0 on lane 0

    uint z[36];
    {
        const uint4* hp = (const uint4*)(ht + tok * 256 + s * 64);
#pragma unroll
        for (int i = 0; i < 8; ++i) {
            uint4 v = hp[i];
            z[4 * i + 0] = v.x;
            z[4 * i + 1] = v.y;
            z[4 * i + 2] = v.z;
            z[4 * i + 3] = v.w;
        }
        const float* xp = x + tok * 12 + 7;
        float x0 = xp[s];
        float x1 = (s == 0) ? xp[4] : 0.f;
        z[32] = pk_rtz(x0, x1);
        z[33] = bz;
        z[34] = 0;
        z[35] = 0;
    }

    layer_big<36, 256, 32>(mp.w0, wl, zbuf, z, tid, s, s1, s2);
#pragma unroll
    for (int i = 0; i < 32; ++i) z[i] = zbuf[tid * 33 + i];
    z[32] = bz; z[33] = 0; z[34] = 0; z[35] = 0;

    layer_big<36, 128, 32>(mp.w1, wl, zbuf, z, tid, s, s1, s2);
#pragma unroll
    for (int i = 0; i < 16; ++i) z[i] = zbuf[tid * 33 + i];
    z[16] = bz; z[17] = 0; z[18] = 0; z[19] = 0;

    layer_big<20, 64, 32>(mp.w2, wl, zbuf, z, tid, s, s1, s2);
#pragma unroll
    for (int i = 0; i < 8; ++i) z[i] = zbuf[tid * 33 + i];
    z[8] = bz; z[9] = 0; z[10] = 0; z[11] = 0;

    // stage L3..L6 (2288 uints contiguous)
    __syncthreads();
    {
        const uint4* src = (const uint4*)mp.wt;
        uint4* dstv = (uint4*)wl;
        for (int idx = tid; idx < 572; idx += 256) dstv[idx] = src[idx];
    }
    __syncthreads();

    layer_comp<12, 32>(wl + 0, z, zbuf, 0, tid, s, s1, s2);
#pragma unroll
    for (int i = 0; i < 4; ++i) z[i] = zbuf[tid * 33 + i];
    z[4] = bz; z[5] = 0; z[6] = 0; z[7] = 0;

    layer_comp<8, 16>(wl + 1536, z, zbuf, 0, tid, s, s1, s2);
    z[0] = zbuf[tid * 33 + 0];
    z[1] = zbuf[tid * 33 + 1];
    z[2] = bz;
    z[3] = 0;

    layer_comp<4, 8>(wl + 2048, z, zbuf, 0, tid, s, s1, s2);
    z[0] = zbuf[tid * 33 + 0];
    z[1] = bz;
    z[2] = 0;
    z[3] = 0;

    // L7 head (N=7), bias in K, no activation
    {
        const uint* wb = wl + 2176;
#pragma unroll
        for (int n = 0; n < 7; ++n) {
            const uint4 wq = *(const uint4*)(wb + (n * 4 + s) * 4);
            float a = 0.f;
            a = fdot2(u2h(z[0]), u2h(wq.x), a);
            a = fdot2(u2h(z[1]), u2h(wq.y), a);
            a = fdot2(u2h(z[2]), u2h(wq.z), a);
            a = fdot2(u2h(z[3]), u2h(wq.w), a);
            a += dpp_xor1(a);
            a += dpp_xor2(a);
            if ((n & 3) == s) out[tok * 7 + n] = a;
        }
    }
}

// ============ launch ============
extern "C" void kernel_launch(void* const* d_in, const int* in_sizes, int n_in,
                              void* d_out, int out_size, void* d_ws, size_t ws_size,
                              hipStream_t stream) {
    const float* x = (const float*)d_in[0];
    const float* Wih = (const float*)d_in[1];
    const float* Whh = (const float*)d_in[2];
    const float* bih = (const float*)d_in[3];
    const float* bhh = (const float*)d_in[4];
    const float* W[7];
    const float* bb[7];
    for (int j = 0; j < 7; ++j) {
        W[j] = (const float*)d_in[5 + 2 * j];
        bb[j] = (const float*)d_in[6 + 2 * j];
    }
    float* out = (float*)d_out;

    static const int Kd[7] = {261, 256, 128, 64, 32, 16, 8};
    static const int Nd[7] = {256, 128, 64, 32, 16, 8, 7};
    static const int PJd[7] = {33, 32, 16, 8, 4, 2, 1};
    static const int UQd[7] = {36, 36, 20, 12, 8, 4, 4};

    char* ws = (char*)d_ws;
    f16* ht = (f16*)ws;  // 128 MiB (permuted layout)
    size_t off = (size_t)NTOK * HH * 2;
    uint* Wsw = (uint*)(ws + off);
    off += (size_t)256 * 128 * 4;
    uint* wp[7];
    static const size_t tail_off[4] = {0, 1536, 2048, 2176};  // uints within wt
    uint* wt = nullptr;
    for (int j = 0; j < 7; ++j) {
        if (j < 3) {
            wp[j] = (uint*)(ws + off);
            off += (size_t)Nd[j] * 4 * UQd[j] * 4;
        } else {
            if (j == 3) { wt = (uint*)(ws + off); off += 2288 * 4; }
            wp[j] = wt + tail_off[j - 3];
        }
    }

    rnn_wswz_kernel<<<128, 256, 0, stream>>>(Whh, Wsw);
    for (int j = 0; j < 7; ++j) {
        int tot = Nd[j] * 4 * UQd[j];
        mlp_wpad_kernel<<<(tot + 255) / 256, 256, 0, stream>>>(W[j], bb[j], wp[j], Nd[j], Kd[j],
                                                               PJd[j], UQd[j]);
    }

    rnn_kernel<<<BB, 256, 0, stream>>>(x, Wsw, Wih, bih, bhh, ht, out + (size_t)NTOK * 7);

    MlpP mp;
    mp.w0 = wp[0];
    mp.w1 = wp[1];
    mp.w2 = wp[2];
    mp.wt = wt;
    mlp_kernel<<<NTOK / 64, 256, 0, stream>>>(ht, x, mp, out);
}